// Round 7
// baseline (379.859 us; speedup 1.0000x reference)
//
#include <hip/hip_runtime.h>
#include <hip/hip_bf16.h>

#define B_   4
#define N_   16384
#define T_   65536
static constexpr float SCALE_F = 0.17677669529663687f; // 32^-0.5

typedef __attribute__((ext_vector_type(8))) short bf16x8;
typedef __attribute__((ext_vector_type(4))) float f32x4;

#define BAR() __builtin_amdgcn_s_barrier()
#define WAIT(vm) asm volatile("s_waitcnt vmcnt(" #vm ") lgkmcnt(0)" ::: "memory")

template<int N>
static __device__ __forceinline__ void waitv() {
    if constexpr (N <= 0)      asm volatile("s_waitcnt vmcnt(0) lgkmcnt(0)" ::: "memory");
    else if constexpr (N == 2) asm volatile("s_waitcnt vmcnt(2) lgkmcnt(0)" ::: "memory");
    else if constexpr (N == 4) asm volatile("s_waitcnt vmcnt(4) lgkmcnt(0)" ::: "memory");
    else                       asm volatile("s_waitcnt vmcnt(6) lgkmcnt(0)" ::: "memory");
}

static __device__ __forceinline__ unsigned pk2bf(float lo, float hi) {
    __hip_bfloat162 t = __float22bfloat162_rn(make_float2(lo, hi));
    union { __hip_bfloat162 h; unsigned u; } c; c.h = t; return c.u;
}
static __device__ __forceinline__ unsigned short f2bf(float f) {
    unsigned u = __float_as_uint(f);
    u += 0x7fffu + ((u >> 16) & 1u);
    return (unsigned short)(u >> 16);
}
// async global->LDS, 16B per lane; dst = wave-uniform base + lane*16
static __device__ __forceinline__ void gl_lds16(const void* g, void* l) {
    __builtin_amdgcn_global_load_lds(
        (const __attribute__((address_space(1))) unsigned int*)g,
        (__attribute__((address_space(3))) unsigned int*)l, 16, 0, 0);
}

// ---------------- prep: Wt_bf (3 blocks) + S1t/cvec (257 blocks) ------------
__global__ __launch_bounds__(256) void prep_all(
    const float* __restrict__ Wq, const float* __restrict__ Wk,
    const float* __restrict__ Wv, unsigned short* __restrict__ Wt,
    const float* __restrict__ Wr, const float* __restrict__ br,
    const float* __restrict__ Wout, const float* __restrict__ bout,
    float* __restrict__ S1t, float* __restrict__ cvec)
{
    const int blk = blockIdx.x;
    if (blk < 3) {
        const float* W = (blk == 0) ? Wq : (blk == 1) ? Wk : Wv;
        unsigned short* dst = Wt + (size_t)blk * 65536 + (size_t)threadIdx.x * 256;
        #pragma unroll 4
        for (int kb = 0; kb < 32; ++kb) {
            float v[8];
            #pragma unroll
            for (int e = 0; e < 8; ++e) v[e] = W[(kb*8 + e)*256 + threadIdx.x];
            uint4 w;
            w.x = pk2bf(v[0], v[1]); w.y = pk2bf(v[2], v[3]);
            w.z = pk2bf(v[4], v[5]); w.w = pk2bf(v[6], v[7]);
            *reinterpret_cast<uint4*>(dst + kb*8) = w;
        }
        return;
    }
    const int i = blk - 3, j = threadIdx.x;
    if (i < 256) {
        const int h = i >> 5, dd = i & 31;
        float s = 0.f;
        #pragma unroll 8
        for (int dp = 0; dp < 32; ++dp)
            s = fmaf(Wr[dd*32 + dp], Wout[(h*32 + dp)*256 + j], s);
        S1t[(size_t)j*256 + i] = s;
    } else {
        float cj = bout[j];
        for (int r = 0; r < 256; ++r) cj = fmaf(br[r & 31], Wout[r*256 + j], cj);
        cvec[j] = cj;
    }
}

// ---------------- K1 ablation family: QKV projection -------------------------
// r5 structure (A+B via global_load_lds, 3 buffers, counted vmcnt).
// AON: A path (HBM read + LDS + pack). BON: B path. MON: MFMA vs VALU mix.
// Stores always execute (consume acc), so nothing upstream can be DCE'd.
template<int AON, int BON, int MON>
__global__ __launch_bounds__(256) void proj_abl(
    const float* __restrict__ states, const float* __restrict__ agent_qs,
    const float* __restrict__ obs, const unsigned short* __restrict__ Wt,
    const float* __restrict__ bq, const float* __restrict__ bk,
    const float* __restrict__ bv,
    unsigned short* __restrict__ q_bf, unsigned short* __restrict__ k_bf,
    unsigned short* __restrict__ v_bf)
{
    constexpr int OPS = (AON ? 2 : 0) + (BON ? 4 : 0);
    __shared__ __align__(16) float          As[3][64*32];   // 3 x 8KB
    __shared__ __align__(16) unsigned short Bs[3][256*32];  // 3 x 16KB

    const int tid = threadIdx.x;
    const int z  = blockIdx.y;
    const int t0 = blockIdx.x * 64;

    const float* X = (z == 0) ? states : (z == 1) ? agent_qs : obs;
    const unsigned short* Bt = Wt + (size_t)z * 65536;
    const float* bias = (z == 0) ? bq : (z == 1) ? bk : bv;
    unsigned short* Y = (z == 0) ? q_bf : (z == 1) ? k_bf : v_bf;
    const bool doabs = (z == 0);

    const int wid = tid >> 6, lane = tid & 63;
    const int l15 = lane & 15, g = lane >> 4;
    const int wc = wid;

    // column permutation: frag coord n' -> true col c = [n'5][n'3:2][n'4][n'1:0]
    int ntrue[4];
    #pragma unroll
    for (int ni = 0; ni < 4; ++ni) {
        int np = ni*16 + l15;
        int c = (np & 32) | ((np & 12) << 1) | ((np & 16) >> 2) | (np & 3);
        ntrue[ni] = wc*64 + c;
    }

    const int srow_lane = lane >> 3;
    const int schunk = (lane & 7) ^ (lane >> 3);
    auto stage = [&](int buf, int step) {
        const int k0 = step * 32;
        if constexpr (BON) {
            #pragma unroll
            for (int j = 0; j < 4; ++j) {
                int n = wid*64 + j*16 + (lane >> 2);
                int cs = (lane & 3) ^ (n & 3) ^ ((n >> 2) & 3);
                gl_lds16(Bt + (size_t)n*256 + k0 + cs*8,
                         &Bs[buf][(wid*64 + j*16)*32]);
            }
        }
        if constexpr (AON) {
            #pragma unroll
            for (int i = 0; i < 2; ++i) {
                int r = (wid*2 + i)*8 + srow_lane;
                gl_lds16(X + (size_t)(t0 + r)*256 + k0 + schunk*4,
                         &As[buf][(wid*2 + i)*256]);
            }
        }
    };
    auto dsreadB = [&](int buf, bf16x8* bb) {
        #pragma unroll
        for (int ni = 0; ni < 4; ++ni) {
            int n2 = ntrue[ni];
            int slot = g ^ (n2 & 3) ^ ((n2 >> 2) & 3);
            bb[ni] = *reinterpret_cast<const bf16x8*>(&Bs[buf][n2*32 + slot*8]);
        }
    };
    auto readApack = [&](int buf, bf16x8* a) {
        #pragma unroll
        for (int mi = 0; mi < 4; ++mi) {
            int m = mi*16 + l15;
            int x = m & 7;
            f32x4 lo = *reinterpret_cast<const f32x4*>(&As[buf][m*32 + ((2*g)  ^x)*4]);
            f32x4 hi = *reinterpret_cast<const f32x4*>(&As[buf][m*32 + ((2*g+1)^x)*4]);
            union { unsigned u[4]; bf16x8 v; } cc;
            cc.u[0] = pk2bf(lo[0], lo[1]);
            cc.u[1] = pk2bf(lo[2], lo[3]);
            cc.u[2] = pk2bf(hi[0], hi[1]);
            cc.u[3] = pk2bf(hi[2], hi[3]);
            a[mi] = cc.v;
        }
    };

    f32x4 acc[4][4];
    #pragma unroll
    for (int mi = 0; mi < 4; ++mi)
        #pragma unroll
        for (int ni = 0; ni < 4; ++ni) acc[mi][ni] = (f32x4){0.f,0.f,0.f,0.f};

    auto compute = [&](const bf16x8* bb, const bf16x8* a) {
        if constexpr (MON) {
            #pragma unroll
            for (int mi = 0; mi < 4; ++mi)
                #pragma unroll
                for (int ni = 0; ni < 4; ++ni)
                    acc[mi][ni] = __builtin_amdgcn_mfma_f32_16x16x32_bf16(
                        bb[ni], a[mi], acc[mi][ni], 0, 0, 0);
        } else {
            #pragma unroll
            for (int mi = 0; mi < 4; ++mi)
                #pragma unroll
                for (int ni = 0; ni < 4; ++ni) {
                    union { bf16x8 s; f32x4 f; } ua, ub;
                    ua.s = a[mi]; ub.s = bb[ni];
                    acc[mi][ni] += ua.f;
                    acc[mi][ni] += ub.f;
                }
        }
    };

    stage(0, 0);
    stage(1, 1);
    waitv<OPS>(); BAR();

    int br_ = 0, bw_ = 2;
    for (int s = 0; s < 6; ++s) {
        bf16x8 bb[4] = {}, a[4] = {};
        if constexpr (BON) dsreadB(br_, bb);
        if constexpr (AON) readApack(br_, a);
        stage(bw_, s + 2);
        compute(bb, a);
        waitv<OPS>(); BAR();
        br_ = (br_ == 2) ? 0 : br_ + 1;
        bw_ = (bw_ == 2) ? 0 : bw_ + 1;
    }
    {   // s = 6 (step 8 doesn't exist: no stage)
        bf16x8 bb[4] = {}, a[4] = {};
        if constexpr (BON) dsreadB(br_, bb);
        if constexpr (AON) readApack(br_, a);
        compute(bb, a);
        waitv<0>(); BAR();
        br_ = (br_ == 2) ? 0 : br_ + 1;
    }
    {   // s = 7
        bf16x8 bb[4] = {}, a[4] = {};
        if constexpr (BON) dsreadB(br_, bb);
        if constexpr (AON) readApack(br_, a);
        compute(bb, a);
    }

    // epilogue: store s covers true cols wc*64 + s*32 + g*8 + [0,8)
    #pragma unroll
    for (int s = 0; s < 2; ++s) {
        int colb = wc*64 + s*32 + g*8;
        float4 b0 = *reinterpret_cast<const float4*>(bias + colb);
        float4 b1 = *reinterpret_cast<const float4*>(bias + colb + 4);
        #pragma unroll
        for (int mi = 0; mi < 4; ++mi) {
            int m = t0 + mi*16 + l15;
            float y0 = acc[mi][2*s  ][0] + b0.x;
            float y1 = acc[mi][2*s  ][1] + b0.y;
            float y2 = acc[mi][2*s  ][2] + b0.z;
            float y3 = acc[mi][2*s  ][3] + b0.w;
            float y4 = acc[mi][2*s+1][0] + b1.x;
            float y5 = acc[mi][2*s+1][1] + b1.y;
            float y6 = acc[mi][2*s+1][2] + b1.z;
            float y7 = acc[mi][2*s+1][3] + b1.w;
            if (doabs) {
                y0 = fabsf(y0); y1 = fabsf(y1); y2 = fabsf(y2); y3 = fabsf(y3);
                y4 = fabsf(y4); y5 = fabsf(y5); y6 = fabsf(y6); y7 = fabsf(y7);
            }
            uint4 pk;
            pk.x = pk2bf(y0, y1); pk.y = pk2bf(y2, y3);
            pk.z = pk2bf(y4, y5); pk.w = pk2bf(y6, y7);
            *reinterpret_cast<uint4*>(Y + (size_t)m*256 + colb) = pk;
        }
    }
}

// ---------------- pools: partial softmax pooling ----------------------------
__global__ __launch_bounds__(512) void pool_partial(
    const unsigned short* __restrict__ data,
    const float* __restrict__ wqa, const float* __restrict__ wka,
    const float* __restrict__ part_in, float* __restrict__ part_out, int mode)
{
    const int bh = blockIdx.x, ch = blockIdx.y;
    const int b = bh >> 3, h = bh & 7;
    const int tid = threadIdx.x;

    __shared__ float coef[32];
    __shared__ float s_red[8];
    __shared__ float a_red[8][32];

    if (tid < 32) {
        float cc;
        if (mode == 0) cc = wqa[tid];
        else {
            float num = 0.f, den = 0.f;
            #pragma unroll
            for (int c = 0; c < 8; ++c) {
                num += part_in[(size_t)(bh*8 + c)*40 + tid];
                den += part_in[(size_t)(bh*8 + c)*40 + 32];
            }
            cc = (num / den) * wka[tid];
        }
        coef[tid] = cc * SCALE_F;
    }
    __syncthreads();
    float cf[32];
    #pragma unroll
    for (int d = 0; d < 32; ++d) cf[d] = coef[d];

    float s = 0.f;
    float acc[32];
    #pragma unroll
    for (int d = 0; d < 32; ++d) acc[d] = 0.f;

    const unsigned short* base = data + (size_t)b * N_ * 256 + h * 32;
    for (int n = ch*2048 + tid; n < (ch + 1)*2048; n += 512) {
        const uint4* p = reinterpret_cast<const uint4*>(base + (size_t)n * 256);
        float qv[32];
        #pragma unroll
        for (int gg = 0; gg < 4; ++gg) {
            uint4 r = p[gg];
            unsigned w0 = r.x, w1 = r.y, w2 = r.z, w3 = r.w;
            qv[gg*8+0] = __uint_as_float(w0 << 16);
            qv[gg*8+1] = __uint_as_float(w0 & 0xffff0000u);
            qv[gg*8+2] = __uint_as_float(w1 << 16);
            qv[gg*8+3] = __uint_as_float(w1 & 0xffff0000u);
            qv[gg*8+4] = __uint_as_float(w2 << 16);
            qv[gg*8+5] = __uint_as_float(w2 & 0xffff0000u);
            qv[gg*8+6] = __uint_as_float(w3 << 16);
            qv[gg*8+7] = __uint_as_float(w3 & 0xffff0000u);
        }
        float l = 0.f;
        #pragma unroll
        for (int d = 0; d < 32; ++d) l = fmaf(qv[d], cf[d], l);
        float e = expf(l);
        s += e;
        #pragma unroll
        for (int d = 0; d < 32; ++d) acc[d] = fmaf(e, qv[d], acc[d]);
    }

    #pragma unroll
    for (int off = 1; off < 64; off <<= 1) {
        s += __shfl_xor(s, off);
        #pragma unroll
        for (int d = 0; d < 32; ++d) acc[d] += __shfl_xor(acc[d], off);
    }
    const int wave = tid >> 6, lane = tid & 63;
    if (lane == 0) {
        s_red[wave] = s;
        #pragma unroll
        for (int d = 0; d < 32; ++d) a_red[wave][d] = acc[d];
    }
    __syncthreads();
    if (tid < 32) {
        float num = 0.f, den = 0.f;
        #pragma unroll
        for (int w2 = 0; w2 < 8; ++w2) { num += a_red[w2][tid]; den += s_red[w2]; }
        part_out[(size_t)(bh*8 + ch)*40 + tid] = num;
        if (tid == 0) part_out[(size_t)(bh*8 + ch)*40 + 32] = den;
    }
}

// ---------------- Wcat_t[b][n][k] bf16 (gk computed inline from part_k) -----
__global__ __launch_bounds__(256) void build_wcat_t(
    const float* __restrict__ part_k, const float* __restrict__ S1t,
    const float* __restrict__ Wout, unsigned short* __restrict__ Wcat_t)
{
    const int b = blockIdx.x, n = blockIdx.y, k = threadIdx.x;
    const int h = k >> 5, d = k & 31;
    float num = 0.f, den = 0.f;
    #pragma unroll
    for (int c = 0; c < 8; ++c) {
        num += part_k[(size_t)((b*8 + h)*8 + c)*40 + d];
        den += part_k[(size_t)((b*8 + h)*8 + c)*40 + 32];
    }
    const float gkv = num / den;
    unsigned short* dst = Wcat_t + (size_t)(b*256 + n) * 512;
    dst[k]       = f2bf(gkv * S1t[(size_t)n*256 + k]);
    dst[k + 256] = f2bf(Wout[(size_t)k*256 + n]);
}

// ---------------- K4: out = [v|q] @ Wcat_t[b]^T + cvec, A+B via gl_lds ------
__global__ __launch_bounds__(256) void out_mfma(
    const unsigned short* __restrict__ v_bf, const unsigned short* __restrict__ q_bf,
    const unsigned short* __restrict__ Wcat_t, const float* __restrict__ cvec,
    float* __restrict__ out)
{
    __shared__ __align__(16) unsigned short As[3][64*32];   // 3 x 4KB
    __shared__ __align__(16) unsigned short Bs[3][256*32];  // 3 x 16KB

    const int tid = threadIdx.x;
    const int t0 = blockIdx.x * 64;
    const int b  = t0 >> 14;
    const unsigned short* Wb = Wcat_t + (size_t)b * 256 * 512;

    const int wid = tid >> 6, lane = tid & 63;
    const int l15 = lane & 15, g = lane >> 4, wc = wid;

    const int sr = wid*16 + (lane >> 2);
    const int stc = (lane & 3) ^ (sr & 3) ^ ((sr >> 2) & 3);
    auto stage = [&](int buf, int step) {
        const int k0 = step * 32;
        #pragma unroll
        for (int j = 0; j < 4; ++j) {
            int n = wid*64 + j*16 + (lane >> 2);
            int cs = (lane & 3) ^ (n & 3) ^ ((n >> 2) & 3);
            gl_lds16(Wb + (size_t)n*512 + k0 + cs*8,
                     &Bs[buf][(wid*64 + j*16)*32]);
        }
        const unsigned short* src = (k0 < 256) ? v_bf : q_bf;
        const int ks = k0 & 255;
        gl_lds16(src + (size_t)(t0 + sr)*256 + ks + stc*8, &As[buf][wid*512]);
    };

    f32x4 acc[4][4];
    #pragma unroll
    for (int mi = 0; mi < 4; ++mi)
        #pragma unroll
        for (int ni = 0; ni < 4; ++ni) acc[mi][ni] = (f32x4){0.f,0.f,0.f,0.f};

    auto step_body = [&](int buf) {
        bf16x8 bb[4], a[4];
        #pragma unroll
        for (int ni = 0; ni < 4; ++ni) {
            int n2 = wc*64 + ni*16 + l15;
            int slot = g ^ (n2 & 3) ^ ((n2 >> 2) & 3);
            bb[ni] = *reinterpret_cast<const bf16x8*>(&Bs[buf][n2*32 + slot*8]);
        }
        #pragma unroll
        for (int mi = 0; mi < 4; ++mi) {
            int m = mi*16 + l15;
            int cc = g ^ (m & 3) ^ ((m >> 2) & 3);
            a[mi] = *reinterpret_cast<const bf16x8*>(&As[buf][m*32 + cc*8]);
        }
        #pragma unroll
        for (int mi = 0; mi < 4; ++mi)
            #pragma unroll
            for (int ni = 0; ni < 4; ++ni)
                acc[mi][ni] = __builtin_amdgcn_mfma_f32_16x16x32_bf16(
                    bb[ni], a[mi], acc[mi][ni], 0, 0, 0);
    };

    stage(0, 0);
    stage(1, 1);
    WAIT(5); BAR();

    int br_ = 0, bw_ = 2;
    for (int s = 0; s < 14; ++s) {
        stage(bw_, s + 2);
        step_body(br_);
        WAIT(5); BAR();
        br_ = (br_ == 2) ? 0 : br_ + 1;
        bw_ = (bw_ == 2) ? 0 : bw_ + 1;
    }
    {   // s = 14
        step_body(br_);
        WAIT(0); BAR();
        br_ = (br_ == 2) ? 0 : br_ + 1;
    }
    step_body(br_);   // s = 15

    #pragma unroll
    for (int ni = 0; ni < 4; ++ni) {
        int colb = wc*64 + ni*16 + g*4;
        float4 cv = *reinterpret_cast<const float4*>(cvec + colb);
        #pragma unroll
        for (int mi = 0; mi < 4; ++mi) {
            int m = t0 + mi*16 + l15;
            float4 o;
            o.x = acc[mi][ni][0] + cv.x;
            o.y = acc[mi][ni][1] + cv.y;
            o.z = acc[mi][ni][2] + cv.z;
            o.w = acc[mi][ni][3] + cv.w;
            *reinterpret_cast<float4*>(out + (size_t)m*256 + colb) = o;
        }
    }
}

extern "C" void kernel_launch(void* const* d_in, const int* in_sizes, int n_in,
                              void* d_out, int out_size, void* d_ws, size_t ws_size,
                              hipStream_t stream)
{
    const float* states   = (const float*)d_in[0];
    const float* agent_qs = (const float*)d_in[1];
    const float* obs      = (const float*)d_in[2];
    const float* Wq   = (const float*)d_in[3];
    const float* bq   = (const float*)d_in[4];
    const float* Wk   = (const float*)d_in[5];
    const float* bk   = (const float*)d_in[6];
    const float* Wv   = (const float*)d_in[7];
    const float* bv   = (const float*)d_in[8];
    const float* wq_attn = (const float*)d_in[9];
    const float* wk_attn = (const float*)d_in[10];
    const float* Wr   = (const float*)d_in[11];
    const float* br   = (const float*)d_in[12];
    const float* Wout = (const float*)d_in[13];
    const float* bout = (const float*)d_in[14];
    float* out = (float*)d_out;

    char* w = (char*)d_ws;
    unsigned short* q_bf = (unsigned short*)w; w += (size_t)T_ * 256 * 2;
    unsigned short* k_bf = (unsigned short*)w; w += (size_t)T_ * 256 * 2;
    unsigned short* v_bf = (unsigned short*)w; w += (size_t)T_ * 256 * 2;
    unsigned short* Wt_bf   = (unsigned short*)w; w += (size_t)3 * 65536 * 2;
    unsigned short* Wcat_t  = (unsigned short*)w; w += (size_t)4 * 256 * 512 * 2;
    float* part_q = (float*)w; w += (size_t)256 * 40 * sizeof(float);
    float* part_k = (float*)w; w += (size_t)256 * 40 * sizeof(float);
    float* S1t  = (float*)w; w += (size_t)256 * 256 * sizeof(float);
    float* cvec = (float*)w; w += 256 * sizeof(float);

    prep_all<<<dim3(260), 256, 0, stream>>>(Wq, Wk, Wv, Wt_bf,
                                            Wr, br, Wout, bout, S1t, cvec);

    // ---- ablation probes (write garbage to q/k/v; overwritten by real) ----
    proj_abl<1,1,0><<<dim3(1024, 3), 256, 0, stream>>>(   // no MFMA
        states, agent_qs, obs, Wt_bf, bq, bk, bv, q_bf, k_bf, v_bf);
    proj_abl<0,1,1><<<dim3(1024, 3), 256, 0, stream>>>(   // no A path
        states, agent_qs, obs, Wt_bf, bq, bk, bv, q_bf, k_bf, v_bf);
    proj_abl<1,0,1><<<dim3(1024, 3), 256, 0, stream>>>(   // no B path
        states, agent_qs, obs, Wt_bf, bq, bk, bv, q_bf, k_bf, v_bf);
    // ---- real projection (must be last of the family) ----
    proj_abl<1,1,1><<<dim3(1024, 3), 256, 0, stream>>>(
        states, agent_qs, obs, Wt_bf, bq, bk, bv, q_bf, k_bf, v_bf);

    pool_partial<<<dim3(32, 8), 512, 0, stream>>>(q_bf, wq_attn, wk_attn,
                                                  part_q, part_q, 0);
    pool_partial<<<dim3(32, 8), 512, 0, stream>>>(k_bf, wq_attn, wk_attn,
                                                  part_q, part_k, 1);
    build_wcat_t<<<dim3(4, 256), 256, 0, stream>>>(part_k, S1t, Wout, Wcat_t);
    out_mfma<<<dim3(1024), 256, 0, stream>>>(v_bf, q_bf, Wcat_t, cvec, out);
}

// Round 8
// 268.224 us; speedup vs baseline: 1.4162x; 1.4162x over previous
//
#include <hip/hip_runtime.h>
#include <hip/hip_bf16.h>

#define B_   4
#define N_   16384
#define T_   65536
static constexpr float SCALE_F = 0.17677669529663687f; // 32^-0.5

typedef __attribute__((ext_vector_type(8))) short bf16x8;
typedef __attribute__((ext_vector_type(4))) float f32x4;

#define BAR() __builtin_amdgcn_s_barrier()
#define WAIT0() asm volatile("s_waitcnt vmcnt(0) lgkmcnt(0)" ::: "memory")

static __device__ __forceinline__ unsigned pk2bf(float lo, float hi) {
    __hip_bfloat162 t = __float22bfloat162_rn(make_float2(lo, hi));
    union { __hip_bfloat162 h; unsigned u; } c; c.h = t; return c.u;
}
static __device__ __forceinline__ unsigned short f2bf(float f) {
    unsigned u = __float_as_uint(f);
    u += 0x7fffu + ((u >> 16) & 1u);
    return (unsigned short)(u >> 16);
}
// async global->LDS, 16B per lane; dst = wave-uniform base + lane*16
static __device__ __forceinline__ void gl_lds16(const void* g, void* l) {
    __builtin_amdgcn_global_load_lds(
        (const __attribute__((address_space(1))) unsigned int*)g,
        (__attribute__((address_space(3))) unsigned int*)l, 16, 0, 0);
}

// ---------------- prep: Wt_bf (3 blocks) + S1t/cvec (257 blocks) ------------
__global__ __launch_bounds__(256) void prep_all(
    const float* __restrict__ Wq, const float* __restrict__ Wk,
    const float* __restrict__ Wv, unsigned short* __restrict__ Wt,
    const float* __restrict__ Wr, const float* __restrict__ br,
    const float* __restrict__ Wout, const float* __restrict__ bout,
    float* __restrict__ S1t, float* __restrict__ cvec)
{
    const int blk = blockIdx.x;
    if (blk < 3) {
        const float* W = (blk == 0) ? Wq : (blk == 1) ? Wk : Wv;
        unsigned short* dst = Wt + (size_t)blk * 65536 + (size_t)threadIdx.x * 256;
        #pragma unroll 4
        for (int kb = 0; kb < 32; ++kb) {
            float v[8];
            #pragma unroll
            for (int e = 0; e < 8; ++e) v[e] = W[(kb*8 + e)*256 + threadIdx.x];
            uint4 w;
            w.x = pk2bf(v[0], v[1]); w.y = pk2bf(v[2], v[3]);
            w.z = pk2bf(v[4], v[5]); w.w = pk2bf(v[6], v[7]);
            *reinterpret_cast<uint4*>(dst + kb*8) = w;
        }
        return;
    }
    const int i = blk - 3, j = threadIdx.x;
    if (i < 256) {
        const int h = i >> 5, dd = i & 31;
        float s = 0.f;
        #pragma unroll 8
        for (int dp = 0; dp < 32; ++dp)
            s = fmaf(Wr[dd*32 + dp], Wout[(h*32 + dp)*256 + j], s);
        S1t[(size_t)j*256 + i] = s;
    } else {
        float cj = bout[j];
        for (int r = 0; r < 256; ++r) cj = fmaf(br[r & 31], Wout[r*256 + j], cj);
        cvec[j] = cj;
    }
}

// ---------------- K1: QKV projection ----------------------------------------
// grid (512, 3), 4 waves. Each block: 4 M-tiles of 32 rows x 256 N, K=256.
// A: whole-K per tile staged via CONTIGUOUS-source gl_lds16 (1KB row per op,
//    lane-XOR permutation within the row), double-buffered 2x32KB, ONE barrier
//    per M-tile. B: L2-resident Wt -> registers, 1-step prefetch.
__global__ __launch_bounds__(256) void proj_mfma(
    const float* __restrict__ states, const float* __restrict__ agent_qs,
    const float* __restrict__ obs, const unsigned short* __restrict__ Wt,
    const float* __restrict__ bq, const float* __restrict__ bk,
    const float* __restrict__ bv,
    unsigned short* __restrict__ q_bf, unsigned short* __restrict__ k_bf,
    unsigned short* __restrict__ v_bf)
{
    __shared__ __align__(16) float As[2][32][256];   // 64 KB

    const int tid = threadIdx.x;
    const int z  = blockIdx.y;
    const int t0base = blockIdx.x * 128;

    const float* X = (z == 0) ? states : (z == 1) ? agent_qs : obs;
    const unsigned short* Bt = Wt + (size_t)z * 65536;
    const float* bias = (z == 0) ? bq : (z == 1) ? bk : bv;
    unsigned short* Y = (z == 0) ? q_bf : (z == 1) ? k_bf : v_bf;
    const bool doabs = (z == 0);

    const int wid = tid >> 6, lane = tid & 63;
    const int l15 = lane & 15, g = lane >> 4;
    const int wc = wid;

    // column permutation: frag coord n' -> true col c = [n'5][n'3:2][n'4][n'1:0]
    const unsigned short* bbase[4];
    #pragma unroll
    for (int ni = 0; ni < 4; ++ni) {
        int np = ni*16 + l15;
        int c = (np & 32) | ((np & 12) << 1) | ((np & 16) >> 2) | (np & 3);
        bbase[ni] = Bt + (size_t)(wc*64 + c) * 256 + g*8;
    }

    // stage: wave w stages local rows w*8+j; source = one contiguous 1KB row,
    // lanes permuted within it (chunk = lane ^ (row&7)) -> logical chunk c
    // lands at LDS chunk c ^ (row&7).
    auto stageA = [&](int buf, int t0) {
        #pragma unroll
        for (int j = 0; j < 8; ++j) {
            int r = wid*8 + j;
            int sc = lane ^ (r & 7);
            gl_lds16(X + (size_t)(t0 + r)*256 + sc*4, &As[buf][r][0]);
        }
    };

    stageA(0, t0base);

    #pragma unroll
    for (int mt = 0; mt < 4; ++mt) {
        const int cur = mt & 1;
        const int t0 = t0base + mt*32;
        WAIT0(); BAR();

        f32x4 acc[2][4];
        #pragma unroll
        for (int mi = 0; mi < 2; ++mi)
            #pragma unroll
            for (int ni = 0; ni < 4; ++ni) acc[mi][ni] = (f32x4){0.f,0.f,0.f,0.f};

        bf16x8 bcur[4];
        #pragma unroll
        for (int ni = 0; ni < 4; ++ni)
            bcur[ni] = *reinterpret_cast<const bf16x8*>(bbase[ni]);

        #pragma unroll
        for (int kk = 0; kk < 8; ++kk) {
            bf16x8 bn[4];
            if (kk < 7) {
                #pragma unroll
                for (int ni = 0; ni < 4; ++ni)
                    bn[ni] = *reinterpret_cast<const bf16x8*>(bbase[ni] + (kk+1)*32);
            }
            bf16x8 a[2];
            #pragma unroll
            for (int mi = 0; mi < 2; ++mi) {
                int m = mi*16 + l15;
                int s = m & 7;
                int c0 = (kk*8 + 2*g)     ^ s;
                int c1 = (kk*8 + 2*g + 1) ^ s;
                f32x4 lo = *reinterpret_cast<const f32x4*>(
                    (const char*)&As[cur][m][0] + c0*16);
                f32x4 hi = *reinterpret_cast<const f32x4*>(
                    (const char*)&As[cur][m][0] + c1*16);
                union { unsigned u[4]; bf16x8 v; } cc;
                cc.u[0] = pk2bf(lo[0], lo[1]);
                cc.u[1] = pk2bf(lo[2], lo[3]);
                cc.u[2] = pk2bf(hi[0], hi[1]);
                cc.u[3] = pk2bf(hi[2], hi[3]);
                a[mi] = cc.v;
            }
            #pragma unroll
            for (int mi = 0; mi < 2; ++mi)
                #pragma unroll
                for (int ni = 0; ni < 4; ++ni)
                    acc[mi][ni] = __builtin_amdgcn_mfma_f32_16x16x32_bf16(
                        bcur[ni], a[mi], acc[mi][ni], 0, 0, 0);
            if (kk < 7) {
                #pragma unroll
                for (int ni = 0; ni < 4; ++ni) bcur[ni] = bn[ni];
            }
        }

        if (mt < 3) stageA(cur ^ 1, t0 + 32);   // youngest vmem ops of this mt

        // epilogue: store s covers true cols wc*64 + s*32 + g*8 + [0,8)
        #pragma unroll
        for (int s = 0; s < 2; ++s) {
            int colb = wc*64 + s*32 + g*8;
            float4 b0 = *reinterpret_cast<const float4*>(bias + colb);
            float4 b1 = *reinterpret_cast<const float4*>(bias + colb + 4);
            #pragma unroll
            for (int mi = 0; mi < 2; ++mi) {
                int m = t0 + mi*16 + l15;
                float y0 = acc[mi][2*s  ][0] + b0.x;
                float y1 = acc[mi][2*s  ][1] + b0.y;
                float y2 = acc[mi][2*s  ][2] + b0.z;
                float y3 = acc[mi][2*s  ][3] + b0.w;
                float y4 = acc[mi][2*s+1][0] + b1.x;
                float y5 = acc[mi][2*s+1][1] + b1.y;
                float y6 = acc[mi][2*s+1][2] + b1.z;
                float y7 = acc[mi][2*s+1][3] + b1.w;
                if (doabs) {
                    y0 = fabsf(y0); y1 = fabsf(y1); y2 = fabsf(y2); y3 = fabsf(y3);
                    y4 = fabsf(y4); y5 = fabsf(y5); y6 = fabsf(y6); y7 = fabsf(y7);
                }
                uint4 pk;
                pk.x = pk2bf(y0, y1); pk.y = pk2bf(y2, y3);
                pk.z = pk2bf(y4, y5); pk.w = pk2bf(y6, y7);
                *reinterpret_cast<uint4*>(Y + (size_t)m*256 + colb) = pk;
            }
        }
    }
}

// ---------------- pools: partial softmax pooling ----------------------------
__global__ __launch_bounds__(512) void pool_partial(
    const unsigned short* __restrict__ data,
    const float* __restrict__ wqa, const float* __restrict__ wka,
    const float* __restrict__ part_in, float* __restrict__ part_out, int mode)
{
    const int bh = blockIdx.x, ch = blockIdx.y;
    const int b = bh >> 3, h = bh & 7;
    const int tid = threadIdx.x;

    __shared__ float coef[32];
    __shared__ float s_red[8];
    __shared__ float a_red[8][32];

    if (tid < 32) {
        float cc;
        if (mode == 0) cc = wqa[tid];
        else {
            float num = 0.f, den = 0.f;
            #pragma unroll
            for (int c = 0; c < 8; ++c) {
                num += part_in[(size_t)(bh*8 + c)*40 + tid];
                den += part_in[(size_t)(bh*8 + c)*40 + 32];
            }
            cc = (num / den) * wka[tid];
        }
        coef[tid] = cc * SCALE_F;
    }
    __syncthreads();
    float cf[32];
    #pragma unroll
    for (int d = 0; d < 32; ++d) cf[d] = coef[d];

    float s = 0.f;
    float acc[32];
    #pragma unroll
    for (int d = 0; d < 32; ++d) acc[d] = 0.f;

    const unsigned short* base = data + (size_t)b * N_ * 256 + h * 32;
    for (int n = ch*2048 + tid; n < (ch + 1)*2048; n += 512) {
        const uint4* p = reinterpret_cast<const uint4*>(base + (size_t)n * 256);
        float qv[32];
        #pragma unroll
        for (int gg = 0; gg < 4; ++gg) {
            uint4 r = p[gg];
            unsigned w0 = r.x, w1 = r.y, w2 = r.z, w3 = r.w;
            qv[gg*8+0] = __uint_as_float(w0 << 16);
            qv[gg*8+1] = __uint_as_float(w0 & 0xffff0000u);
            qv[gg*8+2] = __uint_as_float(w1 << 16);
            qv[gg*8+3] = __uint_as_float(w1 & 0xffff0000u);
            qv[gg*8+4] = __uint_as_float(w2 << 16);
            qv[gg*8+5] = __uint_as_float(w2 & 0xffff0000u);
            qv[gg*8+6] = __uint_as_float(w3 << 16);
            qv[gg*8+7] = __uint_as_float(w3 & 0xffff0000u);
        }
        float l = 0.f;
        #pragma unroll
        for (int d = 0; d < 32; ++d) l = fmaf(qv[d], cf[d], l);
        float e = expf(l);
        s += e;
        #pragma unroll
        for (int d = 0; d < 32; ++d) acc[d] = fmaf(e, qv[d], acc[d]);
    }

    #pragma unroll
    for (int off = 1; off < 64; off <<= 1) {
        s += __shfl_xor(s, off);
        #pragma unroll
        for (int d = 0; d < 32; ++d) acc[d] += __shfl_xor(acc[d], off);
    }
    const int wave = tid >> 6, lane = tid & 63;
    if (lane == 0) {
        s_red[wave] = s;
        #pragma unroll
        for (int d = 0; d < 32; ++d) a_red[wave][d] = acc[d];
    }
    __syncthreads();
    if (tid < 32) {
        float num = 0.f, den = 0.f;
        #pragma unroll
        for (int w2 = 0; w2 < 8; ++w2) { num += a_red[w2][tid]; den += s_red[w2]; }
        part_out[(size_t)(bh*8 + ch)*40 + tid] = num;
        if (tid == 0) part_out[(size_t)(bh*8 + ch)*40 + 32] = den;
    }
}

// ---------------- Wcat_t[b][n][k] bf16 (gk computed inline from part_k) -----
__global__ __launch_bounds__(256) void build_wcat_t(
    const float* __restrict__ part_k, const float* __restrict__ S1t,
    const float* __restrict__ Wout, unsigned short* __restrict__ Wcat_t)
{
    const int b = blockIdx.x, n = blockIdx.y, k = threadIdx.x;
    const int h = k >> 5, d = k & 31;
    float num = 0.f, den = 0.f;
    #pragma unroll
    for (int c = 0; c < 8; ++c) {
        num += part_k[(size_t)((b*8 + h)*8 + c)*40 + d];
        den += part_k[(size_t)((b*8 + h)*8 + c)*40 + 32];
    }
    const float gkv = num / den;
    unsigned short* dst = Wcat_t + (size_t)(b*256 + n) * 512;
    dst[k]       = f2bf(gkv * S1t[(size_t)n*256 + k]);
    dst[k + 256] = f2bf(Wout[(size_t)k*256 + n]);
}

// ---------------- K4: out = [v|q] @ Wcat_t[b]^T + cvec ----------------------
// grid (512), 4 waves. 4 M-tiles of 32 rows x 256 N per block, K=512.
// A: whole-K (v-row 512B + q-row 512B per 1KB op), same skeleton as proj.
__global__ __launch_bounds__(256) void out_mfma(
    const unsigned short* __restrict__ v_bf, const unsigned short* __restrict__ q_bf,
    const unsigned short* __restrict__ Wcat_t, const float* __restrict__ cvec,
    float* __restrict__ out)
{
    __shared__ __align__(16) unsigned short As[2][32][512];  // 64 KB

    const int tid = threadIdx.x;
    const int t0base = blockIdx.x * 128;
    const int b  = blockIdx.x >> 7;
    const unsigned short* Wb = Wcat_t + (size_t)b * 256 * 512;

    const int wid = tid >> 6, lane = tid & 63;
    const int l15 = lane & 15, g = lane >> 4, wc = wid;

    const unsigned short* bbase[4];
    #pragma unroll
    for (int ni = 0; ni < 4; ++ni)
        bbase[ni] = Wb + (size_t)(wc*64 + ni*16 + l15) * 512 + g*8;

    // stage: row r -> LDS [v chunks 0..31 | q chunks 32..63], chunk c of each
    // half stored at position c ^ (r&7) (XOR low3 only, stays in-half).
    auto stageA = [&](int buf, int t0) {
        #pragma unroll
        for (int j = 0; j < 8; ++j) {
            int r = wid*8 + j;
            const unsigned short* src = (lane < 32) ? v_bf : q_bf;
            int sc = (lane & 31) ^ (r & 7);
            gl_lds16(src + (size_t)(t0 + r)*256 + sc*8, &As[buf][r][0]);
        }
    };

    stageA(0, t0base);

    #pragma unroll
    for (int mt = 0; mt < 4; ++mt) {
        const int cur = mt & 1;
        const int t0 = t0base + mt*32;
        WAIT0(); BAR();

        f32x4 acc[2][4];
        #pragma unroll
        for (int mi = 0; mi < 2; ++mi)
            #pragma unroll
            for (int ni = 0; ni < 4; ++ni) acc[mi][ni] = (f32x4){0.f,0.f,0.f,0.f};

        bf16x8 bcur[4];
        #pragma unroll
        for (int ni = 0; ni < 4; ++ni)
            bcur[ni] = *reinterpret_cast<const bf16x8*>(bbase[ni]);

        #pragma unroll
        for (int kk = 0; kk < 16; ++kk) {
            bf16x8 bn[4];
            if (kk < 15) {
                #pragma unroll
                for (int ni = 0; ni < 4; ++ni)
                    bn[ni] = *reinterpret_cast<const bf16x8*>(bbase[ni] + (kk+1)*32);
            }
            bf16x8 a[2];
            #pragma unroll
            for (int mi = 0; mi < 2; ++mi) {
                int m = mi*16 + l15;
                int s = m & 7;
                int c = (kk < 8) ? (((kk*4 + g) ^ s))
                                 : (32 + ((((kk-8)*4 + g)) ^ s));
                a[mi] = *reinterpret_cast<const bf16x8*>(
                    (const char*)&As[cur][m][0] + c*16);
            }
            #pragma unroll
            for (int mi = 0; mi < 2; ++mi)
                #pragma unroll
                for (int ni = 0; ni < 4; ++ni)
                    acc[mi][ni] = __builtin_amdgcn_mfma_f32_16x16x32_bf16(
                        bcur[ni], a[mi], acc[mi][ni], 0, 0, 0);
            if (kk < 15) {
                #pragma unroll
                for (int ni = 0; ni < 4; ++ni) bcur[ni] = bn[ni];
            }
        }

        if (mt < 3) stageA(cur ^ 1, t0 + 32);

        #pragma unroll
        for (int ni = 0; ni < 4; ++ni) {
            int colb = wc*64 + ni*16 + g*4;
            float4 cv = *reinterpret_cast<const float4*>(cvec + colb);
            #pragma unroll
            for (int mi = 0; mi < 2; ++mi) {
                int m = t0 + mi*16 + l15;
                float4 o;
                o.x = acc[mi][ni][0] + cv.x;
                o.y = acc[mi][ni][1] + cv.y;
                o.z = acc[mi][ni][2] + cv.z;
                o.w = acc[mi][ni][3] + cv.w;
                *reinterpret_cast<float4*>(out + (size_t)m*256 + colb) = o;
            }
        }
    }
}

extern "C" void kernel_launch(void* const* d_in, const int* in_sizes, int n_in,
                              void* d_out, int out_size, void* d_ws, size_t ws_size,
                              hipStream_t stream)
{
    const float* states   = (const float*)d_in[0];
    const float* agent_qs = (const float*)d_in[1];
    const float* obs      = (const float*)d_in[2];
    const float* Wq   = (const float*)d_in[3];
    const float* bq   = (const float*)d_in[4];
    const float* Wk   = (const float*)d_in[5];
    const float* bk   = (const float*)d_in[6];
    const float* Wv   = (const float*)d_in[7];
    const float* bv   = (const float*)d_in[8];
    const float* wq_attn = (const float*)d_in[9];
    const float* wk_attn = (const float*)d_in[10];
    const float* Wr   = (const float*)d_in[11];
    const float* br   = (const float*)d_in[12];
    const float* Wout = (const float*)d_in[13];
    const float* bout = (const float*)d_in[14];
    float* out = (float*)d_out;

    char* w = (char*)d_ws;
    unsigned short* q_bf = (unsigned short*)w; w += (size_t)T_ * 256 * 2;
    unsigned short* k_bf = (unsigned short*)w; w += (size_t)T_ * 256 * 2;
    unsigned short* v_bf = (unsigned short*)w; w += (size_t)T_ * 256 * 2;
    unsigned short* Wt_bf   = (unsigned short*)w; w += (size_t)3 * 65536 * 2;
    unsigned short* Wcat_t  = (unsigned short*)w; w += (size_t)4 * 256 * 512 * 2;
    float* part_q = (float*)w; w += (size_t)256 * 40 * sizeof(float);
    float* part_k = (float*)w; w += (size_t)256 * 40 * sizeof(float);
    float* S1t  = (float*)w; w += (size_t)256 * 256 * sizeof(float);
    float* cvec = (float*)w; w += 256 * sizeof(float);

    prep_all<<<dim3(260), 256, 0, stream>>>(Wq, Wk, Wv, Wt_bf,
                                            Wr, br, Wout, bout, S1t, cvec);
    proj_mfma<<<dim3(512, 3), 256, 0, stream>>>(
        states, agent_qs, obs, Wt_bf, bq, bk, bv, q_bf, k_bf, v_bf);
    pool_partial<<<dim3(32, 8), 512, 0, stream>>>(q_bf, wq_attn, wk_attn,
                                                  part_q, part_q, 0);
    pool_partial<<<dim3(32, 8), 512, 0, stream>>>(k_bf, wq_attn, wk_attn,
                                                  part_q, part_k, 1);
    build_wcat_t<<<dim3(4, 256), 256, 0, stream>>>(part_k, S1t, Wout, Wcat_t);
    out_mfma<<<dim3(512), 256, 0, stream>>>(v_bf, q_bf, Wcat_t, cvec, out);
}

// Round 9
// 202.071 us; speedup vs baseline: 1.8798x; 1.3274x over previous
//
#include <hip/hip_runtime.h>
#include <hip/hip_bf16.h>

#define B_   4
#define N_   16384
#define T_   65536
static constexpr float SCALE_F = 0.17677669529663687f; // 32^-0.5

typedef __attribute__((ext_vector_type(8))) short bf16x8;
typedef __attribute__((ext_vector_type(4))) float f32x4;

#define BAR() __builtin_amdgcn_s_barrier()
#define WAIT(vm) asm volatile("s_waitcnt vmcnt(" #vm ") lgkmcnt(0)" ::: "memory")

template<int S> struct IC { static constexpr int v = S; };

static __device__ __forceinline__ unsigned pk2bf(float lo, float hi) {
    __hip_bfloat162 t = __float22bfloat162_rn(make_float2(lo, hi));
    union { __hip_bfloat162 h; unsigned u; } c; c.h = t; return c.u;
}
static __device__ __forceinline__ unsigned short f2bf(float f) {
    unsigned u = __float_as_uint(f);
    u += 0x7fffu + ((u >> 16) & 1u);
    return (unsigned short)(u >> 16);
}
// async global->LDS, 16B per lane; dst = wave-uniform base + lane*16
static __device__ __forceinline__ void gl_lds16(const void* g, void* l) {
    __builtin_amdgcn_global_load_lds(
        (const __attribute__((address_space(1))) unsigned int*)g,
        (__attribute__((address_space(3))) unsigned int*)l, 16, 0, 0);
}

// ---------------- prep: Wt_bf (3 blocks) + S1t/cvec (257 blocks) ------------
__global__ __launch_bounds__(256) void prep_all(
    const float* __restrict__ Wq, const float* __restrict__ Wk,
    const float* __restrict__ Wv, unsigned short* __restrict__ Wt,
    const float* __restrict__ Wr, const float* __restrict__ br,
    const float* __restrict__ Wout, const float* __restrict__ bout,
    float* __restrict__ S1t, float* __restrict__ cvec)
{
    const int blk = blockIdx.x;
    if (blk < 3) {
        const float* W = (blk == 0) ? Wq : (blk == 1) ? Wk : Wv;
        unsigned short* dst = Wt + (size_t)blk * 65536 + (size_t)threadIdx.x * 256;
        #pragma unroll 4
        for (int kb = 0; kb < 32; ++kb) {
            float v[8];
            #pragma unroll
            for (int e = 0; e < 8; ++e) v[e] = W[(kb*8 + e)*256 + threadIdx.x];
            uint4 w;
            w.x = pk2bf(v[0], v[1]); w.y = pk2bf(v[2], v[3]);
            w.z = pk2bf(v[4], v[5]); w.w = pk2bf(v[6], v[7]);
            *reinterpret_cast<uint4*>(dst + kb*8) = w;
        }
        return;
    }
    const int i = blk - 3, j = threadIdx.x;
    if (i < 256) {
        const int h = i >> 5, dd = i & 31;
        float s = 0.f;
        #pragma unroll 8
        for (int dp = 0; dp < 32; ++dp)
            s = fmaf(Wr[dd*32 + dp], Wout[(h*32 + dp)*256 + j], s);
        S1t[(size_t)j*256 + i] = s;
    } else {
        float cj = bout[j];
        for (int r = 0; r < 256; ++r) cj = fmaf(br[r & 31], Wout[r*256 + j], cj);
        cvec[j] = cj;
    }
}

// ---------------- K1: QKV projection, B-in-registers ------------------------
// grid (1024, 3), 256 thr / 4 waves. Tile 64 M x 256 N, K=256, 8 steps.
// B: half-K in regs (breg[4][4], 64 VGPR), one reload at step 4.
// A: 4 LDS bufs, 3-ahead gl_lds16 (2 ops/wave/step), counted vmcnt.
// Inner loop == the r7 "noB" ablation probe (~34us) + MFMA (~free).
__global__ __launch_bounds__(256, 2) void proj_mfma(
    const float* __restrict__ states, const float* __restrict__ agent_qs,
    const float* __restrict__ obs, const unsigned short* __restrict__ Wt,
    const float* __restrict__ bq, const float* __restrict__ bk,
    const float* __restrict__ bv,
    unsigned short* __restrict__ q_bf, unsigned short* __restrict__ k_bf,
    unsigned short* __restrict__ v_bf)
{
    __shared__ __align__(16) float As[4][64*32];   // 4 x 8KB

    const int tid = threadIdx.x;
    const int z  = blockIdx.y;
    const int t0 = blockIdx.x * 64;

    const float* X = (z == 0) ? states : (z == 1) ? agent_qs : obs;
    const unsigned short* Bt = Wt + (size_t)z * 65536;
    const float* bias = (z == 0) ? bq : (z == 1) ? bk : bv;
    unsigned short* Y = (z == 0) ? q_bf : (z == 1) ? k_bf : v_bf;
    const bool doabs = (z == 0);

    const int wid = tid >> 6, lane = tid & 63;
    const int l15 = lane & 15, g = lane >> 4;
    const int wc = wid;

    // column permutation: frag coord n' -> true col c = [n'5][n'3:2][n'4][n'1:0]
    const unsigned short* bbase[4];
    #pragma unroll
    for (int ni = 0; ni < 4; ++ni) {
        int np = ni*16 + l15;
        int c = (np & 32) | ((np & 12) << 1) | ((np & 16) >> 2) | (np & 3);
        bbase[ni] = Bt + (size_t)(wc*64 + c) * 256 + g*8;
    }

    bf16x8 breg[4][4];
    auto loadBhalf = [&](int half) {
        #pragma unroll
        for (int ni = 0; ni < 4; ++ni)
            #pragma unroll
            for (int sl = 0; sl < 4; ++sl)
                breg[ni][sl] = *reinterpret_cast<const bf16x8*>(
                    bbase[ni] + (half*4 + sl)*32);
    };

    const int srow_lane = lane >> 3;
    const int schunk = (lane & 7) ^ (lane >> 3);
    auto stageA = [&](int buf, int step) {
        const int k0 = step * 32;
        #pragma unroll
        for (int i = 0; i < 2; ++i) {
            int r = (wid*2 + i)*8 + srow_lane;
            gl_lds16(X + (size_t)(t0 + r)*256 + k0 + schunk*4,
                     &As[buf][(wid*2 + i)*256]);
        }
    };

    f32x4 acc[4][4];
    #pragma unroll
    for (int mi = 0; mi < 4; ++mi)
        #pragma unroll
        for (int ni = 0; ni < 4; ++ni) acc[mi][ni] = (f32x4){0.f,0.f,0.f,0.f};

    auto body = [&](auto sc) {
        constexpr int s = decltype(sc)::v;
        constexpr int buf = s & 3;
        constexpr int sl  = s & 3;
        bf16x8 a[4];
        #pragma unroll
        for (int mi = 0; mi < 4; ++mi) {
            int m = mi*16 + l15;
            int x = m & 7;
            f32x4 lo = *reinterpret_cast<const f32x4*>(&As[buf][m*32 + ((2*g)  ^x)*4]);
            f32x4 hi = *reinterpret_cast<const f32x4*>(&As[buf][m*32 + ((2*g+1)^x)*4]);
            union { unsigned u[4]; bf16x8 v; } cc;
            cc.u[0] = pk2bf(lo[0], lo[1]);
            cc.u[1] = pk2bf(lo[2], lo[3]);
            cc.u[2] = pk2bf(hi[0], hi[1]);
            cc.u[3] = pk2bf(hi[2], hi[3]);
            a[mi] = cc.v;
        }
        if constexpr (s + 3 < 8) stageA((s + 3) & 3, s + 3);
        #pragma unroll
        for (int mi = 0; mi < 4; ++mi)
            #pragma unroll
            for (int ni = 0; ni < 4; ++ni)
                acc[mi][ni] = __builtin_amdgcn_mfma_f32_16x16x32_bf16(
                    breg[ni][sl], a[mi], acc[mi][ni], 0, 0, 0);
    };

    loadBhalf(0);
    stageA(0, 0); stageA(1, 1); stageA(2, 2);

    WAIT(4); BAR(); body(IC<0>{});
    WAIT(4); BAR(); body(IC<1>{});
    WAIT(4); BAR(); body(IC<2>{});
    WAIT(4); BAR(); body(IC<3>{});
    WAIT(0); BAR(); loadBhalf(1); body(IC<4>{});
    body(IC<5>{});
    body(IC<6>{});
    WAIT(0); BAR(); body(IC<7>{});

    // epilogue: store s covers true cols wc*64 + s*32 + g*8 + [0,8)
    #pragma unroll
    for (int s = 0; s < 2; ++s) {
        int colb = wc*64 + s*32 + g*8;
        float4 b0 = *reinterpret_cast<const float4*>(bias + colb);
        float4 b1 = *reinterpret_cast<const float4*>(bias + colb + 4);
        #pragma unroll
        for (int mi = 0; mi < 4; ++mi) {
            int m = t0 + mi*16 + l15;
            float y0 = acc[mi][2*s  ][0] + b0.x;
            float y1 = acc[mi][2*s  ][1] + b0.y;
            float y2 = acc[mi][2*s  ][2] + b0.z;
            float y3 = acc[mi][2*s  ][3] + b0.w;
            float y4 = acc[mi][2*s+1][0] + b1.x;
            float y5 = acc[mi][2*s+1][1] + b1.y;
            float y6 = acc[mi][2*s+1][2] + b1.z;
            float y7 = acc[mi][2*s+1][3] + b1.w;
            if (doabs) {
                y0 = fabsf(y0); y1 = fabsf(y1); y2 = fabsf(y2); y3 = fabsf(y3);
                y4 = fabsf(y4); y5 = fabsf(y5); y6 = fabsf(y6); y7 = fabsf(y7);
            }
            uint4 pk;
            pk.x = pk2bf(y0, y1); pk.y = pk2bf(y2, y3);
            pk.z = pk2bf(y4, y5); pk.w = pk2bf(y6, y7);
            *reinterpret_cast<uint4*>(Y + (size_t)m*256 + colb) = pk;
        }
    }
}

// ---------------- pools: partial softmax pooling ----------------------------
__global__ __launch_bounds__(512) void pool_partial(
    const unsigned short* __restrict__ data,
    const float* __restrict__ wqa, const float* __restrict__ wka,
    const float* __restrict__ part_in, float* __restrict__ part_out, int mode)
{
    const int bh = blockIdx.x, ch = blockIdx.y;
    const int b = bh >> 3, h = bh & 7;
    const int tid = threadIdx.x;

    __shared__ float coef[32];
    __shared__ float s_red[8];
    __shared__ float a_red[8][32];

    if (tid < 32) {
        float cc;
        if (mode == 0) cc = wqa[tid];
        else {
            float num = 0.f, den = 0.f;
            #pragma unroll
            for (int c = 0; c < 8; ++c) {
                num += part_in[(size_t)(bh*8 + c)*40 + tid];
                den += part_in[(size_t)(bh*8 + c)*40 + 32];
            }
            cc = (num / den) * wka[tid];
        }
        coef[tid] = cc * SCALE_F;
    }
    __syncthreads();
    float cf[32];
    #pragma unroll
    for (int d = 0; d < 32; ++d) cf[d] = coef[d];

    float s = 0.f;
    float acc[32];
    #pragma unroll
    for (int d = 0; d < 32; ++d) acc[d] = 0.f;

    const unsigned short* base = data + (size_t)b * N_ * 256 + h * 32;
    for (int n = ch*2048 + tid; n < (ch + 1)*2048; n += 512) {
        const uint4* p = reinterpret_cast<const uint4*>(base + (size_t)n * 256);
        float qv[32];
        #pragma unroll
        for (int gg = 0; gg < 4; ++gg) {
            uint4 r = p[gg];
            unsigned w0 = r.x, w1 = r.y, w2 = r.z, w3 = r.w;
            qv[gg*8+0] = __uint_as_float(w0 << 16);
            qv[gg*8+1] = __uint_as_float(w0 & 0xffff0000u);
            qv[gg*8+2] = __uint_as_float(w1 << 16);
            qv[gg*8+3] = __uint_as_float(w1 & 0xffff0000u);
            qv[gg*8+4] = __uint_as_float(w2 << 16);
            qv[gg*8+5] = __uint_as_float(w2 & 0xffff0000u);
            qv[gg*8+6] = __uint_as_float(w3 << 16);
            qv[gg*8+7] = __uint_as_float(w3 & 0xffff0000u);
        }
        float l = 0.f;
        #pragma unroll
        for (int d = 0; d < 32; ++d) l = fmaf(qv[d], cf[d], l);
        float e = expf(l);
        s += e;
        #pragma unroll
        for (int d = 0; d < 32; ++d) acc[d] = fmaf(e, qv[d], acc[d]);
    }

    #pragma unroll
    for (int off = 1; off < 64; off <<= 1) {
        s += __shfl_xor(s, off);
        #pragma unroll
        for (int d = 0; d < 32; ++d) acc[d] += __shfl_xor(acc[d], off);
    }
    const int wave = tid >> 6, lane = tid & 63;
    if (lane == 0) {
        s_red[wave] = s;
        #pragma unroll
        for (int d = 0; d < 32; ++d) a_red[wave][d] = acc[d];
    }
    __syncthreads();
    if (tid < 32) {
        float num = 0.f, den = 0.f;
        #pragma unroll
        for (int w2 = 0; w2 < 8; ++w2) { num += a_red[w2][tid]; den += s_red[w2]; }
        part_out[(size_t)(bh*8 + ch)*40 + tid] = num;
        if (tid == 0) part_out[(size_t)(bh*8 + ch)*40 + 32] = den;
    }
}

// ---------------- Wcat_t[b][n][k] bf16 (gk computed inline from part_k) -----
__global__ __launch_bounds__(256) void build_wcat_t(
    const float* __restrict__ part_k, const float* __restrict__ S1t,
    const float* __restrict__ Wout, unsigned short* __restrict__ Wcat_t)
{
    const int b = blockIdx.x, n = blockIdx.y, k = threadIdx.x;
    const int h = k >> 5, d = k & 31;
    float num = 0.f, den = 0.f;
    #pragma unroll
    for (int c = 0; c < 8; ++c) {
        num += part_k[(size_t)((b*8 + h)*8 + c)*40 + d];
        den += part_k[(size_t)((b*8 + h)*8 + c)*40 + 32];
    }
    const float gkv = num / den;
    unsigned short* dst = Wcat_t + (size_t)(b*256 + n) * 512;
    dst[k]       = f2bf(gkv * S1t[(size_t)n*256 + k]);
    dst[k + 256] = f2bf(Wout[(size_t)k*256 + n]);
}

// ---------------- K4: out = [v|q] @ Wcat_t[b]^T + cvec, B-in-registers ------
// grid (1024), 256 thr / 4 waves. Tile 64 M x 256 N, K=512, 16 steps.
// B: half-K in regs (breg[4][8], 128 VGPR), one reload at step 8.
// A: 4 LDS bufs, 3-ahead gl_lds16 (1 op/wave/step), counted vmcnt.
__global__ __launch_bounds__(256, 2) void out_mfma(
    const unsigned short* __restrict__ v_bf, const unsigned short* __restrict__ q_bf,
    const unsigned short* __restrict__ Wcat_t, const float* __restrict__ cvec,
    float* __restrict__ out)
{
    __shared__ __align__(16) unsigned short As[4][64*32];  // 4 x 4KB

    const int tid = threadIdx.x;
    const int t0 = blockIdx.x * 64;
    const int b  = t0 >> 14;
    const unsigned short* Wb = Wcat_t + (size_t)b * 256 * 512;

    const int wid = tid >> 6, lane = tid & 63;
    const int l15 = lane & 15, g = lane >> 4, wc = wid;

    const unsigned short* bbase[4];
    #pragma unroll
    for (int ni = 0; ni < 4; ++ni)
        bbase[ni] = Wb + (size_t)(wc*64 + ni*16 + l15) * 512 + g*8;

    bf16x8 breg[4][8];
    auto loadBhalf = [&](int half) {
        #pragma unroll
        for (int ni = 0; ni < 4; ++ni)
            #pragma unroll
            for (int sl = 0; sl < 8; ++sl)
                breg[ni][sl] = *reinterpret_cast<const bf16x8*>(
                    bbase[ni] + (half*8 + sl)*32);
    };

    const int sr = wid*16 + (lane >> 2);
    const int stc = (lane & 3) ^ (sr & 3) ^ ((sr >> 2) & 3);
    auto stageA = [&](int buf, int step) {
        const int k0 = step * 32;
        const unsigned short* src = (k0 < 256) ? v_bf : q_bf;
        int ks = k0 & 255;
        gl_lds16(src + (size_t)(t0 + sr)*256 + ks + stc*8, &As[buf][wid*512]);
    };

    f32x4 acc[4][4];
    #pragma unroll
    for (int mi = 0; mi < 4; ++mi)
        #pragma unroll
        for (int ni = 0; ni < 4; ++ni) acc[mi][ni] = (f32x4){0.f,0.f,0.f,0.f};

    auto body = [&](auto sc) {
        constexpr int s = decltype(sc)::v;
        constexpr int buf = s & 3;
        constexpr int sl  = s & 7;
        bf16x8 a[4];
        #pragma unroll
        for (int mi = 0; mi < 4; ++mi) {
            int m = mi*16 + l15;
            int cc = g ^ (m & 3) ^ ((m >> 2) & 3);
            a[mi] = *reinterpret_cast<const bf16x8*>(&As[buf][m*32 + cc*8]);
        }
        if constexpr (s + 3 < 16) stageA((s + 3) & 3, s + 3);
        #pragma unroll
        for (int mi = 0; mi < 4; ++mi)
            #pragma unroll
            for (int ni = 0; ni < 4; ++ni)
                acc[mi][ni] = __builtin_amdgcn_mfma_f32_16x16x32_bf16(
                    breg[ni][sl], a[mi], acc[mi][ni], 0, 0, 0);
    };

    loadBhalf(0);
    stageA(0, 0); stageA(1, 1); stageA(2, 2);

    WAIT(2); BAR(); body(IC<0>{});
    WAIT(2); BAR(); body(IC<1>{});
    WAIT(2); BAR(); body(IC<2>{});
    WAIT(2); BAR(); body(IC<3>{});
    WAIT(2); BAR(); body(IC<4>{});
    WAIT(2); BAR(); body(IC<5>{});
    WAIT(2); BAR(); body(IC<6>{});
    WAIT(2); BAR(); body(IC<7>{});
    WAIT(0); BAR(); loadBhalf(1); body(IC<8>{});
    WAIT(2); BAR(); body(IC<9>{});
    WAIT(2); BAR(); body(IC<10>{});
    WAIT(2); BAR(); body(IC<11>{});
    WAIT(2); BAR(); body(IC<12>{});
    WAIT(2); BAR(); body(IC<13>{});
    WAIT(1); BAR(); body(IC<14>{});
    WAIT(0); BAR(); body(IC<15>{});

    #pragma unroll
    for (int ni = 0; ni < 4; ++ni) {
        int colb = wc*64 + ni*16 + g*4;
        float4 cv = *reinterpret_cast<const float4*>(cvec + colb);
        #pragma unroll
        for (int mi = 0; mi < 4; ++mi) {
            int m = t0 + mi*16 + l15;
            float4 o;
            o.x = acc[mi][ni][0] + cv.x;
            o.y = acc[mi][ni][1] + cv.y;
            o.z = acc[mi][ni][2] + cv.z;
            o.w = acc[mi][ni][3] + cv.w;
            *reinterpret_cast<float4*>(out + (size_t)m*256 + colb) = o;
        }
    }
}

extern "C" void kernel_launch(void* const* d_in, const int* in_sizes, int n_in,
                              void* d_out, int out_size, void* d_ws, size_t ws_size,
                              hipStream_t stream)
{
    const float* states   = (const float*)d_in[0];
    const float* agent_qs = (const float*)d_in[1];
    const float* obs      = (const float*)d_in[2];
    const float* Wq   = (const float*)d_in[3];
    const float* bq   = (const float*)d_in[4];
    const float* Wk   = (const float*)d_in[5];
    const float* bk   = (const float*)d_in[6];
    const float* Wv   = (const float*)d_in[7];
    const float* bv   = (const float*)d_in[8];
    const float* wq_attn = (const float*)d_in[9];
    const float* wk_attn = (const float*)d_in[10];
    const float* Wr   = (const float*)d_in[11];
    const float* br   = (const float*)d_in[12];
    const float* Wout = (const float*)d_in[13];
    const float* bout = (const float*)d_in[14];
    float* out = (float*)d_out;

    char* w = (char*)d_ws;
    unsigned short* q_bf = (unsigned short*)w; w += (size_t)T_ * 256 * 2;
    unsigned short* k_bf = (unsigned short*)w; w += (size_t)T_ * 256 * 2;
    unsigned short* v_bf = (unsigned short*)w; w += (size_t)T_ * 256 * 2;
    unsigned short* Wt_bf   = (unsigned short*)w; w += (size_t)3 * 65536 * 2;
    unsigned short* Wcat_t  = (unsigned short*)w; w += (size_t)4 * 256 * 512 * 2;
    float* part_q = (float*)w; w += (size_t)256 * 40 * sizeof(float);
    float* part_k = (float*)w; w += (size_t)256 * 40 * sizeof(float);
    float* S1t  = (float*)w; w += (size_t)256 * 256 * sizeof(float);
    float* cvec = (float*)w; w += 256 * sizeof(float);

    prep_all<<<dim3(260), 256, 0, stream>>>(Wq, Wk, Wv, Wt_bf,
                                            Wr, br, Wout, bout, S1t, cvec);
    proj_mfma<<<dim3(1024, 3), 256, 0, stream>>>(
        states, agent_qs, obs, Wt_bf, bq, bk, bv, q_bf, k_bf, v_bf);
    pool_partial<<<dim3(32, 8), 512, 0, stream>>>(q_bf, wq_attn, wk_attn,
                                                  part_q, part_q, 0);
    pool_partial<<<dim3(32, 8), 512, 0, stream>>>(k_bf, wq_attn, wk_attn,
                                                  part_q, part_k, 1);
    build_wcat_t<<<dim3(4, 256), 256, 0, stream>>>(part_k, S1t, Wout, Wcat_t);
    out_mfma<<<dim3(1024), 256, 0, stream>>>(v_bf, q_bf, Wcat_t, cvec, out);
}